// Round 7
// baseline (125.686 us; speedup 1.0000x reference)
//
#include <hip/hip_runtime.h>

#define PI_F 3.14159265358979323846f
#define SC (1.0f/65536.0f)

__device__ __forceinline__ float2 cmul(float2 a, float2 b){
  return make_float2(fmaf(a.x, b.x, -(a.y*b.y)), fmaf(a.x, b.y, a.y*b.x));
}
__device__ __forceinline__ float2 cadd(float2 a, float2 b){ return make_float2(a.x+b.x, a.y+b.y); }
__device__ __forceinline__ float2 csub(float2 a, float2 b){ return make_float2(a.x-b.x, a.y-b.y); }

// kept (unshifted) frequency indices: [0,44) U [211,256); compact c: k<44 -> c=k, k>=211 -> c=k-167
__device__ __forceinline__ bool keepf(int k){ return (k < 44) || (k >= 211); }
// base-4 digit reversal of a 6-bit lane id
__device__ __forceinline__ int rev4(int l){ return ((l&3)<<4) | (l&12) | (l>>4); }

// e^{SIGN*i*th}
template<int SIGN>
__device__ __forceinline__ float2 twf(float th){
  float sn, cs; __sincosf(th, &sn, &cs);
  return make_float2(cs, (SIGN<0)? -sn : sn);
}

__device__ __forceinline__ float2 shfl2(float2 v, int src){
  return make_float2(__shfl(v.x, src, 64), __shfl(v.y, src, 64));
}

// cross-lane radix-4 stage at stride S (16/4/1) of a 64-pt DFT, one value/lane.
// fwd (SIGN<0): butterfly (own digit r), then *= e^{-2pi i m r/(4S)}
// inv (SIGN>0): *= e^{+2pi i m r/(4S)}, then conj butterfly
template<int SIGN, int S>
__device__ __forceinline__ float2 xstage(float2 v, int l, float2 w){
  const int r = (S==16) ? (l>>4) : (S==4) ? ((l>>2)&3) : (l&3);
  const int base = l - r*S;
  if(SIGN>0 && S>1) v = cmul(v, w);
  float2 z0 = shfl2(v, base);
  float2 z1 = shfl2(v, base + S);
  float2 z2 = shfl2(v, base + 2*S);
  float2 z3 = shfl2(v, base + 3*S);
  float2 e = cadd(z0,z2), f = csub(z0,z2), g = cadd(z1,z3), h = csub(z1,z3);
  float2 ihv = (SIGN<0) ? make_float2(h.y, -h.x) : make_float2(-h.y, h.x);
  const bool even = ((r&1)==0);
  float2 c0 = even ? e : f;
  float2 c1 = even ? g : ihv;
  const float s = (r<2) ? 1.0f : -1.0f;
  float2 o = make_float2(fmaf(s, c1.x, c0.x), fmaf(s, c1.y, c0.y));
  if(SIGN<0 && S>1) o = cmul(o, w);
  return o;
}

// forward 256-pt: in d[p]=x[l+64p] -> out d[q]=X[4*rev4(l)+q]. Unnormalized. No barriers.
__device__ __forceinline__ void fft256f(float2 d[4], int l){
  { // intra-lane radix-4 over stride 64 + twiddle W256^{l q}
    float2 e=cadd(d[0],d[2]), f=csub(d[0],d[2]), g=cadd(d[1],d[3]), h=csub(d[1],d[3]);
    float2 ihv = make_float2(h.y, -h.x);             // -i*h
    float2 A0=cadd(e,g), A1=cadd(f,ihv), A2=csub(e,g), A3=csub(f,ihv);
    float2 w1 = twf<-1>((2.0f*PI_F/256.0f)*(float)l);
    float2 w2 = cmul(w1,w1), w3 = cmul(w2,w1);
    d[0]=A0; d[1]=cmul(A1,w1); d[2]=cmul(A2,w2); d[3]=cmul(A3,w3);
  }
  const float2 wB = twf<-1>((2.0f*PI_F/64.0f)*(float)((l&15)*(l>>4)));
  const float2 wC = twf<-1>((2.0f*PI_F/16.0f)*(float)((l&3)*((l>>2)&3)));
  const float2 one = make_float2(1.f, 0.f);
#pragma unroll
  for(int q=0;q<4;++q){
    d[q] = xstage<-1,16>(d[q], l, wB);
    d[q] = xstage<-1,4 >(d[q], l, wC);
    d[q] = xstage<-1,1 >(d[q], l, one);
  }
}

// inverse 256-pt (DIT mirror): in d[q]=Y[4*rev4(l)+q] -> out d[p]=Z[l+64p]. Unnormalized.
__device__ __forceinline__ void ifft256f(float2 d[4], int l){
  const float2 wB = twf<1>((2.0f*PI_F/64.0f)*(float)((l&15)*(l>>4)));
  const float2 wC = twf<1>((2.0f*PI_F/16.0f)*(float)((l&3)*((l>>2)&3)));
  const float2 one = make_float2(1.f, 0.f);
#pragma unroll
  for(int q=0;q<4;++q){
    d[q] = xstage<1,1 >(d[q], l, one);
    d[q] = xstage<1,4 >(d[q], l, wC);
    d[q] = xstage<1,16>(d[q], l, wB);
  }
  // intra-lane: conj twiddle then conj butterfly
  float2 w1 = twf<1>((2.0f*PI_F/256.0f)*(float)l);
  float2 w2 = cmul(w1,w1), w3 = cmul(w2,w1);
  float2 u0=d[0], u1=cmul(d[1],w1), u2=cmul(d[2],w2), u3=cmul(d[3],w3);
  float2 e=cadd(u0,u2), f=csub(u0,u2), g=cadd(u1,u3), h=csub(u1,u3);
  float2 ihv = make_float2(-h.y, h.x);               // +i*h
  d[0]=cadd(e,g); d[1]=cadd(f,ihv); d[2]=csub(e,g); d[3]=csub(f,ihv);
}

// K1: d = target - refer, register row FFT, keep 89 w, write compact TRANSPOSED dkwT[b][c][h].
//     Block 2048: composite weights into wbuf (weights staged in LDS first).
__global__ __launch_bounds__(256) void k_rowfft(const float* __restrict__ tgt,
                                                const float* __restrict__ ref,
                                                float2* __restrict__ dkwT,
                                                const float* __restrict__ w1g,
                                                const float* __restrict__ b1g,
                                                const float* __restrict__ w2g,
                                                const float* __restrict__ b2g,
                                                float* __restrict__ wbuf){
  __shared__ __align__(16) float2 cT[89][4];
  __shared__ float wsh[2370];
  const int tid = threadIdx.x;
  if(blockIdx.x == 2048){
    float* w1s = wsh;            // 1152
    float* w2s = wsh + 1152;     // 1152
    float* b1s = wsh + 2304;     // 64
    float* b2s = wsh + 2368;     // 2
    for(int t = tid; t < 1152; t += 256){ w1s[t] = w1g[t]; w2s[t] = w2g[t]; }
    if(tid < 64) b1s[tid] = b1g[tid];
    if(tid < 2)  b2s[tid] = b2g[tid];
    __syncthreads();
    for(int t = tid; t < 444; t += 256){
      if(t < 100){
        const int ux = t % 5, uy = (t/5) % 5, ic = (t/25) & 1, oc = t/50;
        float acc = 0.f;
        for(int mc = 0; mc < 64; ++mc)
          for(int dy = 0; dy < 3; ++dy){
            int ky = uy - dy; if((unsigned)ky >= 3u) continue;
            for(int dx = 0; dx < 3; ++dx){
              int kx = ux - dx; if((unsigned)kx >= 3u) continue;
              acc = fmaf(w2s[((oc*64+mc)*3+dy)*3+dx], w1s[((mc*2+ic)*3+ky)*3+kx], acc);
            }
          }
        wbuf[t] = acc;
      } else if(t < 102){
        const int oc = t - 100;
        float acc = b2s[oc];
        for(int mc = 0; mc < 64; ++mc){
          float s = 0.f;
          for(int d = 0; d < 9; ++d) s += w2s[(oc*64+mc)*9 + d];
          acc = fmaf(s, b1s[mc], acc);
        }
        wbuf[t] = acc;
      } else if(t < 426){
        const int g = t - 102;
        const int oc = g / 162, r1 = g - oc*162;
        const int ic = r1 / 81,  r2 = r1 - ic*81;
        const int d  = r2 / 9,   k9 = r2 - d*9;
        float acc = 0.f;
        for(int mc = 0; mc < 64; ++mc)
          acc = fmaf(w2s[(oc*64+mc)*9 + d], w1s[(mc*2+ic)*9 + k9], acc);
        wbuf[t] = acc;
      } else {
        const int i = t - 426, oc = i / 9, d = i - oc*9;
        float acc = 0.f;
        for(int mc = 0; mc < 64; ++mc)
          acc = fmaf(w2s[(oc*64+mc)*9 + d], b1s[mc], acc);
        wbuf[t] = acc;
      }
    }
    return;
  }
  const int wv = tid >> 6, ln = tid & 63;
  const int line = blockIdx.x*4 + wv;
  const int b = line >> 8, h = line & 255;
  const size_t base0 = ((size_t)(b*2 + 0)*256 + h)*256;
  const size_t base1 = ((size_t)(b*2 + 1)*256 + h)*256;
  float2 d[4];
#pragma unroll
  for(int p = 0; p < 4; ++p){
    const int w = ln + 64*p;
    d[p] = make_float2(tgt[base0 + w] - ref[base0 + w],
                       tgt[base1 + w] - ref[base1 + w]);
  }
  fft256f(d, ln);
  const int t4 = rev4(ln);
#pragma unroll
  for(int q = 0; q < 4; ++q){
    const int k = 4*t4 + q;
    if(keepf(k)){
      const int c = (k < 44) ? k : (k - 167);
      cT[c][wv] = d[q];
    }
  }
  __syncthreads();
  // cooperative transposed compact write: 89 c x 4 h, 32B chunks
  const int b0 = (blockIdx.x*4) >> 8;
  const int h0 = (blockIdx.x*4) & 255;
  if(tid < 178){
    const int c = tid >> 1, half = tid & 1;
    *(float4*)(dkwT + (size_t)(b0*89 + c)*256 + h0 + half*2) = *(float4*)&cT[c][half*2];
  }
}

// K2: per kept column: register FFT along H, mask, register IFFT. dkwT rows -> dkwC[b][h][c].
__global__ __launch_bounds__(256) void k_colfft(const float2* __restrict__ dkwT,
                                                float2* __restrict__ dkwC){
  __shared__ float2 sT[4][256];
  const int wv = threadIdx.x >> 6, ln = threadIdx.x & 63;
  const int lineIdx = blockIdx.x*4 + wv;   // 2848 total = b*89 + c
  const float2* src = dkwT + (size_t)lineIdx*256;
  float2 d[4];
#pragma unroll
  for(int p = 0; p < 4; ++p) d[p] = src[ln + 64*p];
  fft256f(d, ln);
  const int t4 = rev4(ln);
#pragma unroll
  for(int q = 0; q < 4; ++q){
    const int k = 4*t4 + q;
    if(!keepf(k)) d[q] = make_float2(0.f, 0.f);
  }
  ifft256f(d, ln);
#pragma unroll
  for(int p = 0; p < 4; ++p) sT[wv][ln + 64*p] = d[p];
  __syncthreads();
  for(int idx = threadIdx.x; idx < 1024; idx += 256){
    const int cw = idx & 3, h = idx >> 2;
    const int li = blockIdx.x*4 + cw;
    const int bb = li / 89, cc = li - bb*89;
    dkwC[((size_t)bb*256 + h)*89 + cc] = sT[cw][h];
  }
}

// K3: per 8-row strip: register row-IFFT of 12 rows into LDS (+refer), ONE barrier,
//     composite 5x5 conv with float4 pair reads, self-contained border fixup.
__global__ __launch_bounds__(256) void k_strip(const float2* __restrict__ dkwC,
                                               const float* __restrict__ ref,
                                               const float* __restrict__ wb,
                                               float* __restrict__ out){
  __shared__ __align__(16) float2 strip[12][264];   // strip idx = image_x + 2
  __shared__ float wefs[102];
  __shared__ float Gs[324];
  __shared__ float Cbs[18];
  const int tid = threadIdx.x, wv = tid >> 6, ln = tid & 63;
  const int b = blockIdx.y, y0 = blockIdx.x * 8;

  for(int i = tid; i < 444; i += 256){
    float v = wb[i];
    if(i < 102) wefs[i] = v;
    else if(i < 426) Gs[i - 102] = v;
    else Cbs[i - 426] = v;
  }

  // ---- register row IFFT: 3 rows per wave, no barriers ----
  const int t4 = rev4(ln);
  for(int i = 0; i < 3; ++i){
    const int sr = wv*3 + i;
    const int gy = y0 - 2 + sr;
    const bool gv = ((unsigned)gy < 256u);
    const float2* row = dkwC + ((size_t)b*256 + (gv ? gy : 0))*89;
    // prefetch refer (coalesced scalar loads)
    float r0v[4], r1v[4];
    if(gv){
      const size_t base0 = ((size_t)(b*2 + 0)*256 + gy)*256;
      const size_t base1 = ((size_t)(b*2 + 1)*256 + gy)*256;
#pragma unroll
      for(int p = 0; p < 4; ++p){
        r0v[p] = ref[base0 + ln + 64*p];
        r1v[p] = ref[base1 + ln + 64*p];
      }
    } else {
#pragma unroll
      for(int p = 0; p < 4; ++p){ r0v[p] = 0.f; r1v[p] = 0.f; }
    }
    float2 d[4];
#pragma unroll
    for(int q = 0; q < 4; ++q){
      const int k = 4*t4 + q;
      float2 v = make_float2(0.f, 0.f);
      if(gv && keepf(k)){
        const int c = (k < 44) ? k : (k - 167);
        v = row[c];
      }
      d[q] = v;
    }
    ifft256f(d, ln);
#pragma unroll
    for(int p = 0; p < 4; ++p){
      const int w = ln + 64*p;
      strip[sr][2 + w] = make_float2(fmaf(d[p].x, SC, r0v[p]),
                                     fmaf(d[p].y, SC, r1v[p]));
    }
    if(ln < 2){
      strip[sr][ln] = make_float2(0.f, 0.f);
      strip[sr][258 + ln] = make_float2(0.f, 0.f);
    }
  }
  __syncthreads();

  // ---- conv phase: thread = (row, pair-lane); pixel pairs (ox, ox+1), ox even ----
  const int rr_ = tid >> 5;          // 0..7
  const int pp  = tid & 31;
  const int oy  = y0 + rr_;
  const bool yin = (oy != 0) && (oy != 255);
  const size_t ob0 = ((size_t)(b*2 + 0)*256 + oy)*256;
  const size_t ob1 = ((size_t)(b*2 + 1)*256 + oy)*256;
#pragma unroll
  for(int j = 0; j < 4; ++j){
    const int ox = 2*pp + 64*j;
    float p0a = wefs[100], p0b = wefs[101];
    float p1a = p0a,       p1b = p0b;
#pragma unroll
    for(int uy = 0; uy < 5; ++uy){
      const float4* rp = (const float4*)&strip[rr_ + uy][ox];
      const float4 q0 = rp[0], q1 = rp[1], q2 = rp[2];
      const float* wA = &wefs[uy*5];
      const float* wB = &wefs[25 + uy*5];
      const float* wC = &wefs[50 + uy*5];
      const float* wD = &wefs[75 + uy*5];
      p0a = fmaf(q0.x, wA[0], fmaf(q0.y, wB[0], p0a));
      p0b = fmaf(q0.x, wC[0], fmaf(q0.y, wD[0], p0b));
      p1a = fmaf(q0.z, wA[0], fmaf(q0.w, wB[0], p1a));
      p1b = fmaf(q0.z, wC[0], fmaf(q0.w, wD[0], p1b));
      p0a = fmaf(q0.z, wA[1], fmaf(q0.w, wB[1], p0a));
      p0b = fmaf(q0.z, wC[1], fmaf(q0.w, wD[1], p0b));
      p1a = fmaf(q1.x, wA[1], fmaf(q1.y, wB[1], p1a));
      p1b = fmaf(q1.x, wC[1], fmaf(q1.y, wD[1], p1b));
      p0a = fmaf(q1.x, wA[2], fmaf(q1.y, wB[2], p0a));
      p0b = fmaf(q1.x, wC[2], fmaf(q1.y, wD[2], p0b));
      p1a = fmaf(q1.z, wA[2], fmaf(q1.w, wB[2], p1a));
      p1b = fmaf(q1.z, wC[2], fmaf(q1.w, wD[2], p1b));
      p0a = fmaf(q1.z, wA[3], fmaf(q1.w, wB[3], p0a));
      p0b = fmaf(q1.z, wC[3], fmaf(q1.w, wD[3], p0b));
      p1a = fmaf(q2.x, wA[3], fmaf(q2.y, wB[3], p1a));
      p1b = fmaf(q2.x, wC[3], fmaf(q2.y, wD[3], p1b));
      p0a = fmaf(q2.x, wA[4], fmaf(q2.y, wB[4], p0a));
      p0b = fmaf(q2.x, wC[4], fmaf(q2.y, wD[4], p0b));
      p1a = fmaf(q2.z, wA[4], fmaf(q2.w, wB[4], p1a));
      p1b = fmaf(q2.z, wC[4], fmaf(q2.w, wD[4], p1b));
    }
    if(yin){
      if(ox != 0 && ox != 254){
        *(float2*)(out + ob0 + ox) = make_float2(p0a, p1a);
        *(float2*)(out + ob1 + ox) = make_float2(p0b, p1b);
      } else if(ox == 0){
        out[ob0 + 1] = p1a; out[ob1 + 1] = p1b;
      } else { // ox == 254
        out[ob0 + 254] = p0a; out[ob1 + 254] = p0b;
      }
    }
  }

  // ---- border fixup: full recompute + G/Cb correction, all from strip LDS ----
  const int nb = 16 + ((y0 == 0) ? 254 : 0) + ((y0 == 248) ? 254 : 0);
  for(int idx = tid; idx < nb; idx += 256){
    int py2, ox2;
    if(idx < 16){ py2 = idx >> 1; ox2 = (idx & 1) ? 255 : 0; }
    else {
      int e = idx - 16;
      if(y0 == 0 && e < 254){ py2 = 0; ox2 = 1 + e; }
      else { if(y0 == 0) e -= 254; py2 = 7; ox2 = 1 + e; }
    }
    const int oy2 = y0 + py2;
    float a0 = wefs[100], a1 = wefs[101];
#pragma unroll
    for(int uy = 0; uy < 5; ++uy)
#pragma unroll
      for(int ux = 0; ux < 5; ++ux){
        const float2 v = strip[py2 + uy][ox2 + ux];
        const int wi = uy*5 + ux;
        a0 = fmaf(v.x, wefs[wi],      fmaf(v.y, wefs[25 + wi], a0));
        a1 = fmaf(v.x, wefs[50 + wi], fmaf(v.y, wefs[75 + wi], a1));
      }
    for(int dy = 0; dy < 3; ++dy)
      for(int dx = 0; dx < 3; ++dx){
        const int gy2 = oy2 + dy - 1, gx2 = ox2 + dx - 1;
        if((unsigned)gy2 < 256u && (unsigned)gx2 < 256u) continue;
        const int d = dy*3 + dx;
        float c0 = Cbs[d], c1 = Cbs[9 + d];
        for(int ky = 0; ky < 3; ++ky){
          const int sy = gy2 + ky - 1;
          if((unsigned)sy >= 256u) continue;
          const int sr2 = sy - y0 + 2;
          for(int kx = 0; kx < 3; ++kx){
            const int sx = gx2 + kx - 1;
            if((unsigned)sx >= 256u) continue;
            const float2 v = strip[sr2][2 + sx];
            const int k9 = ky*3 + kx;
            c0 += Gs[0*81 + d*9 + k9]*v.x + Gs[1*81 + d*9 + k9]*v.y;
            c1 += Gs[2*81 + d*9 + k9]*v.x + Gs[3*81 + d*9 + k9]*v.y;
          }
        }
        a0 -= c0; a1 -= c1;
      }
    out[((size_t)(b*2 + 0)*256 + oy2)*256 + ox2] = a0;
    out[((size_t)(b*2 + 1)*256 + oy2)*256 + ox2] = a1;
  }
}

extern "C" void kernel_launch(void* const* d_in, const int* in_sizes, int n_in,
                              void* d_out, int out_size, void* d_ws, size_t ws_size,
                              hipStream_t stream) {
  const float* tgt = (const float*)d_in[0];
  const float* ref = (const float*)d_in[1];
  const float* w1  = (const float*)d_in[2];
  const float* b1  = (const float*)d_in[3];
  const float* w2  = (const float*)d_in[4];
  const float* b2  = (const float*)d_in[5];
  float* out = (float*)d_out;

  // ws: dkwT @0 (5.84MB), dkwC @8MB (5.84MB), wbuf @16MB (444 f32)
  float2* dkwT = (float2*)d_ws;
  float2* dkwC = (float2*)((char*)d_ws + (size_t)8*1024*1024);
  float*  wbuf = (float*)((char*)d_ws + (size_t)16*1024*1024);

  k_rowfft<<<2049, 256, 0, stream>>>(tgt, ref, dkwT, w1, b1, w2, b2, wbuf);
  k_colfft<<<712,  256, 0, stream>>>(dkwT, dkwC);
  dim3 gs(32, 32);
  k_strip <<<gs,   256, 0, stream>>>(dkwC, ref, wbuf, out);
}

// Round 8
// 117.394 us; speedup vs baseline: 1.0706x; 1.0706x over previous
//
#include <hip/hip_runtime.h>

#define PI_F 3.14159265358979323846f
#define SC (1.0f/65536.0f)

__device__ __forceinline__ float2 cmul(float2 a, float2 b){
  return make_float2(fmaf(a.x, b.x, -(a.y*b.y)), fmaf(a.x, b.y, a.y*b.x));
}
__device__ __forceinline__ float2 cadd(float2 a, float2 b){ return make_float2(a.x+b.x, a.y+b.y); }
__device__ __forceinline__ float2 csub(float2 a, float2 b){ return make_float2(a.x-b.x, a.y-b.y); }

// base-4 digit reversal of a 6-bit lane id
__device__ __forceinline__ int rev4(int l){ return ((l&3)<<4) | (l&12) | (l>>4); }

template<int SIGN>
__device__ __forceinline__ float2 twf(float th){
  float sn, cs; __sincosf(th, &sn, &cs);
  return make_float2(cs, (SIGN<0)? -sn : sn);
}

__device__ __forceinline__ float2 shfl2(float2 v, int src){
  return make_float2(__shfl(v.x, src, 64), __shfl(v.y, src, 64));
}

// cross-lane radix-4 stage at stride S (16/4/1) of a 64-pt DFT, one value/lane.
template<int SIGN, int S>
__device__ __forceinline__ float2 xstage(float2 v, int l, float2 w){
  const int r = (S==16) ? (l>>4) : (S==4) ? ((l>>2)&3) : (l&3);
  const int base = l - r*S;
  if(SIGN>0 && S>1) v = cmul(v, w);
  float2 z0 = shfl2(v, base);
  float2 z1 = shfl2(v, base + S);
  float2 z2 = shfl2(v, base + 2*S);
  float2 z3 = shfl2(v, base + 3*S);
  float2 e = cadd(z0,z2), f = csub(z0,z2), g = cadd(z1,z3), h = csub(z1,z3);
  float2 ihv = (SIGN<0) ? make_float2(h.y, -h.x) : make_float2(-h.y, h.x);
  const bool even = ((r&1)==0);
  float2 c0 = even ? e : f;
  float2 c1 = even ? g : ihv;
  const float s = (r<2) ? 1.0f : -1.0f;
  float2 o = make_float2(fmaf(s, c1.x, c0.x), fmaf(s, c1.y, c0.y));
  if(SIGN<0 && S>1) o = cmul(o, w);
  return o;
}

// fwd2: input d[p] = x[4l+p] (lane-consecutive quad) -> output d[k0] = X[rev4(l) + 64*k0].
// X[k'+64k0] = sum_p W256^{p k'} W4^{p k0} (64DFT_l x[4l+p])[k'],  k' = rev4(l). Unnormalized.
__device__ __forceinline__ void fwd2(float2 d[4], int l, int r4){
  const float2 wB = twf<-1>((2.0f*PI_F/64.0f)*(float)((l&15)*(l>>4)));
  const float2 wC = twf<-1>((2.0f*PI_F/16.0f)*(float)((l&3)*((l>>2)&3)));
  const float2 one = make_float2(1.f, 0.f);
#pragma unroll
  for(int p=0;p<4;++p){
    d[p] = xstage<-1,16>(d[p], l, wB);
    d[p] = xstage<-1,4 >(d[p], l, wC);
    d[p] = xstage<-1,1 >(d[p], l, one);
  }
  float2 w1 = twf<-1>((2.0f*PI_F/256.0f)*(float)r4);
  float2 w2 = cmul(w1,w1), w3 = cmul(w2,w1);
  d[1]=cmul(d[1],w1); d[2]=cmul(d[2],w2); d[3]=cmul(d[3],w3);
  float2 e=cadd(d[0],d[2]), f=csub(d[0],d[2]), g=cadd(d[1],d[3]), h=csub(d[1],d[3]);
  float2 mih = make_float2(h.y, -h.x);     // -i*h
  d[0]=cadd(e,g); d[1]=cadd(f,mih); d[2]=csub(e,g); d[3]=csub(f,mih);
}

// inv2: input d[k0] = Y[rev4(l) + 64*k0] -> output d[p] = z[4l+p]. Unnormalized.
__device__ __forceinline__ void inv2(float2 d[4], int l, int r4){
  {
    float2 e=cadd(d[0],d[2]), f=csub(d[0],d[2]), g=cadd(d[1],d[3]), h=csub(d[1],d[3]);
    float2 pih = make_float2(-h.y, h.x);   // +i*h
    d[0]=cadd(e,g); d[1]=cadd(f,pih); d[2]=csub(e,g); d[3]=csub(f,pih);
  }
  float2 w1 = twf<1>((2.0f*PI_F/256.0f)*(float)r4);
  float2 w2 = cmul(w1,w1), w3 = cmul(w2,w1);
  d[1]=cmul(d[1],w1); d[2]=cmul(d[2],w2); d[3]=cmul(d[3],w3);
  const float2 wB = twf<1>((2.0f*PI_F/64.0f)*(float)((l&15)*(l>>4)));
  const float2 wC = twf<1>((2.0f*PI_F/16.0f)*(float)((l&3)*((l>>2)&3)));
  const float2 one = make_float2(1.f, 0.f);
#pragma unroll
  for(int p=0;p<4;++p){
    d[p] = xstage<1,1 >(d[p], l, one);
    d[p] = xstage<1,4 >(d[p], l, wC);
    d[p] = xstage<1,16>(d[p], l, wB);
  }
}

// kept k = r4 + 64*k0: k0==0 kept iff r4<44 (compact c=r4); k0==3 kept iff r4>=19 (c=25+r4).
// k0==1,2 never kept.

// K1: 512 blocks x 256 thr: block = (batch, 16 rows). d=tgt-ref, fwd2 per row (float4 loads,
//     next-row prefetch), kept coeffs -> padded LDS -> coalesced dkwT[b][c][h] (128B runs).
//     Block 512: composite weights into wbuf.
__global__ __launch_bounds__(256) void k_rowfft(const float* __restrict__ tgt,
                                                const float* __restrict__ ref,
                                                float2* __restrict__ dkwT,
                                                const float* __restrict__ w1g,
                                                const float* __restrict__ b1g,
                                                const float* __restrict__ w2g,
                                                const float* __restrict__ b2g,
                                                float* __restrict__ wbuf){
  __shared__ __align__(16) float2 cT[89][17];   // [c][hh], pad 17 for bank spread
  const int tid = threadIdx.x;
  if(blockIdx.x == 512){
    float* wsh = (float*)cT;          // 3026 floats available, need 2370
    float* w1s = wsh;                 // 1152
    float* w2s = wsh + 1152;          // 1152
    float* b1s = wsh + 2304;          // 64
    float* b2s = wsh + 2368;          // 2
    for(int t = tid; t < 1152; t += 256){ w1s[t] = w1g[t]; w2s[t] = w2g[t]; }
    if(tid < 64) b1s[tid] = b1g[tid];
    if(tid < 2)  b2s[tid] = b2g[tid];
    __syncthreads();
    for(int t = tid; t < 444; t += 256){
      if(t < 100){
        const int ux = t % 5, uy = (t/5) % 5, ic = (t/25) & 1, oc = t/50;
        float acc = 0.f;
        for(int mc = 0; mc < 64; ++mc)
          for(int dy = 0; dy < 3; ++dy){
            int ky = uy - dy; if((unsigned)ky >= 3u) continue;
            for(int dx = 0; dx < 3; ++dx){
              int kx = ux - dx; if((unsigned)kx >= 3u) continue;
              acc = fmaf(w2s[((oc*64+mc)*3+dy)*3+dx], w1s[((mc*2+ic)*3+ky)*3+kx], acc);
            }
          }
        wbuf[t] = acc;
      } else if(t < 102){
        const int oc = t - 100;
        float acc = b2s[oc];
        for(int mc = 0; mc < 64; ++mc){
          float s = 0.f;
          for(int d = 0; d < 9; ++d) s += w2s[(oc*64+mc)*9 + d];
          acc = fmaf(s, b1s[mc], acc);
        }
        wbuf[t] = acc;
      } else if(t < 426){
        const int g = t - 102;
        const int oc = g / 162, r1 = g - oc*162;
        const int ic = r1 / 81,  r2 = r1 - ic*81;
        const int d  = r2 / 9,   k9 = r2 - d*9;
        float acc = 0.f;
        for(int mc = 0; mc < 64; ++mc)
          acc = fmaf(w2s[(oc*64+mc)*9 + d], w1s[(mc*2+ic)*9 + k9], acc);
        wbuf[t] = acc;
      } else {
        const int i = t - 426, oc = i / 9, d = i - oc*9;
        float acc = 0.f;
        for(int mc = 0; mc < 64; ++mc)
          acc = fmaf(w2s[(oc*64+mc)*9 + d], b1s[mc], acc);
        wbuf[t] = acc;
      }
    }
    return;
  }
  const int wv = tid >> 6, ln = tid & 63, r4 = rev4(ln);
  const int b  = blockIdx.x >> 4;
  const int h0 = (blockIdx.x & 15) << 4;
  const float* t0p = tgt + (size_t)(b*2 + 0)*65536;
  const float* t1p = tgt + (size_t)(b*2 + 1)*65536;
  const float* r0p = ref + (size_t)(b*2 + 0)*65536;
  const float* r1p = ref + (size_t)(b*2 + 1)*65536;

  int h = h0 + wv*4;
  float4 c0 = *(const float4*)(t0p + h*256 + 4*ln);
  float4 c1 = *(const float4*)(t1p + h*256 + 4*ln);
  float4 c2 = *(const float4*)(r0p + h*256 + 4*ln);
  float4 c3 = *(const float4*)(r1p + h*256 + 4*ln);
#pragma unroll
  for(int i = 0; i < 4; ++i){
    float4 n0, n1, n2, n3;
    if(i < 3){
      const int h2 = h + 1;
      n0 = *(const float4*)(t0p + h2*256 + 4*ln);
      n1 = *(const float4*)(t1p + h2*256 + 4*ln);
      n2 = *(const float4*)(r0p + h2*256 + 4*ln);
      n3 = *(const float4*)(r1p + h2*256 + 4*ln);
    }
    float2 d[4];
    d[0] = make_float2(c0.x - c2.x, c1.x - c3.x);
    d[1] = make_float2(c0.y - c2.y, c1.y - c3.y);
    d[2] = make_float2(c0.z - c2.z, c1.z - c3.z);
    d[3] = make_float2(c0.w - c2.w, c1.w - c3.w);
    fwd2(d, ln, r4);
    const int hh = wv*4 + i;
    if(r4 < 44) cT[r4][hh]      = d[0];
    if(r4 >= 19) cT[25 + r4][hh] = d[3];
    c0 = n0; c1 = n1; c2 = n2; c3 = n3;
    ++h;
  }
  __syncthreads();
  // coalesced write: per c, 16 h contiguous (128B runs)
  for(int idx = tid; idx < 1424; idx += 256){
    const int c = idx >> 4, hh = idx & 15;
    dkwT[(size_t)(b*89 + c)*256 + h0 + hh] = cT[c][hh];
  }
}

// K2: block = (batch, 8 columns), 512 thr (wave per column). fwd2 along h, h-mask, inv2.
//     Writes dkwC[b][h][c] in 64B c-contiguous runs via LDS stage.
__global__ __launch_bounds__(512) void k_colfft(const float2* __restrict__ dkwT,
                                                float2* __restrict__ dkwC){
  __shared__ __align__(16) float2 sT[8][256];
  const int tid = threadIdx.x, wv = tid >> 6, ln = tid & 63, r4 = rev4(ln);
  const int b  = blockIdx.y;
  const int c0 = blockIdx.x * 8;
  const int c  = c0 + wv;
  if(c < 89){
    const float2* src = dkwT + (size_t)(b*89 + c)*256;
    const float4* s4 = (const float4*)(src + 4*ln);
    float4 p0 = s4[0], p1 = s4[1];
    float2 d[4];
    d[0] = make_float2(p0.x, p0.y);
    d[1] = make_float2(p0.z, p0.w);
    d[2] = make_float2(p1.x, p1.y);
    d[3] = make_float2(p1.z, p1.w);
    fwd2(d, ln, r4);
    // h-mask: keep kh<44 (k0==0, r4<44) and kh>=211 (k0==3, r4>=19)
    if(r4 >= 44) d[0] = make_float2(0.f, 0.f);
    d[1] = make_float2(0.f, 0.f);
    d[2] = make_float2(0.f, 0.f);
    if(r4 < 19) d[3] = make_float2(0.f, 0.f);
    inv2(d, ln, r4);
    float4* o4 = (float4*)&sT[wv][4*ln];
    o4[0] = make_float4(d[0].x, d[0].y, d[1].x, d[1].y);
    o4[1] = make_float4(d[2].x, d[2].y, d[3].x, d[3].y);
  }
  __syncthreads();
#pragma unroll
  for(int t = 0; t < 4; ++t){
    const int idx = tid + 512*t;        // 2048 = 256h x 8c
    const int hh = idx >> 3, cw = idx & 7;
    if(c0 + cw < 89)
      dkwC[((size_t)b*256 + hh)*89 + c0 + cw] = sT[cw][hh];
  }
}

// K3: per 16-row strip (512 blocks): register row-IFFT of 20 rows into LDS (+refer),
//     next-row prefetch, ONE barrier, composite 5x5 conv, self-contained border fixup.
__global__ __launch_bounds__(256) void k_strip(const float2* __restrict__ dkwC,
                                               const float* __restrict__ ref,
                                               const float* __restrict__ wb,
                                               float* __restrict__ out){
  __shared__ __align__(16) float2 strip[20][264];   // strip idx = image_x + 2
  __shared__ float wefs[102];
  __shared__ float Gs[324];
  __shared__ float Cbs[18];
  const int tid = threadIdx.x, wv = tid >> 6, ln = tid & 63, r4 = rev4(ln);
  const int b = blockIdx.y, y0 = blockIdx.x * 16;

  for(int i = tid; i < 444; i += 256){
    float v = wb[i];
    if(i < 102) wefs[i] = v;
    else if(i < 426) Gs[i - 102] = v;
    else Cbs[i - 426] = v;
  }

  const float* rf0 = ref + (size_t)(b*2 + 0)*65536;
  const float* rf1 = ref + (size_t)(b*2 + 1)*65536;
  const float2 z2 = make_float2(0.f, 0.f);
  const float4 z4 = make_float4(0.f, 0.f, 0.f, 0.f);

  // ---- row IFFT: 5 rows per wave, prefetch next row's 4 loads during current FFT ----
  float4 pr0, pr1; float2 pd0, pd3;
  {
    const int gy = y0 - 2 + wv*5;
    const bool gv = ((unsigned)gy < 256u);
    const float2* row = dkwC + ((size_t)b*256 + (gv ? gy : 0))*89;
    pd0 = (gv && r4 < 44)  ? row[r4]      : z2;
    pd3 = (gv && r4 >= 19) ? row[25 + r4] : z2;
    pr0 = gv ? *(const float4*)(rf0 + gy*256 + 4*ln) : z4;
    pr1 = gv ? *(const float4*)(rf1 + gy*256 + 4*ln) : z4;
  }
#pragma unroll
  for(int i = 0; i < 5; ++i){
    float4 r0 = pr0, r1 = pr1;
    float2 d[4]; d[0] = pd0; d[1] = z2; d[2] = z2; d[3] = pd3;
    if(i < 4){
      const int gy2 = y0 - 2 + wv*5 + i + 1;
      const bool gv2 = ((unsigned)gy2 < 256u);
      const float2* row2 = dkwC + ((size_t)b*256 + (gv2 ? gy2 : 0))*89;
      pd0 = (gv2 && r4 < 44)  ? row2[r4]      : z2;
      pd3 = (gv2 && r4 >= 19) ? row2[25 + r4] : z2;
      pr0 = gv2 ? *(const float4*)(rf0 + gy2*256 + 4*ln) : z4;
      pr1 = gv2 ? *(const float4*)(rf1 + gy2*256 + 4*ln) : z4;
    }
    inv2(d, ln, r4);
    const int sr = wv*5 + i;
    float4* w4 = (float4*)&strip[sr][2 + 4*ln];
    w4[0] = make_float4(fmaf(d[0].x, SC, r0.x), fmaf(d[0].y, SC, r1.x),
                        fmaf(d[1].x, SC, r0.y), fmaf(d[1].y, SC, r1.y));
    w4[1] = make_float4(fmaf(d[2].x, SC, r0.z), fmaf(d[2].y, SC, r1.z),
                        fmaf(d[3].x, SC, r0.w), fmaf(d[3].y, SC, r1.w));
    if(ln < 2){
      strip[sr][ln] = z2;
      strip[sr][258 + ln] = z2;
    }
  }
  __syncthreads();

  // ---- conv phase: thread = (row rr_=tid>>4, pair-lane pp=tid&15); ox = 2pp+32j ----
  const int rr_ = tid >> 4;          // 0..15
  const int pp  = tid & 15;
  const int oy  = y0 + rr_;
  const bool yin = (oy != 0) && (oy != 255);
  const size_t ob0 = ((size_t)(b*2 + 0)*256 + oy)*256;
  const size_t ob1 = ((size_t)(b*2 + 1)*256 + oy)*256;
#pragma unroll
  for(int j = 0; j < 8; ++j){
    const int ox = 2*pp + 32*j;
    float p0a = wefs[100], p0b = wefs[101];
    float p1a = p0a,       p1b = p0b;
#pragma unroll
    for(int uy = 0; uy < 5; ++uy){
      const float4* rp = (const float4*)&strip[rr_ + uy][ox];
      const float4 q0 = rp[0], q1 = rp[1], q2 = rp[2];
      const float* wA = &wefs[uy*5];
      const float* wB = &wefs[25 + uy*5];
      const float* wC = &wefs[50 + uy*5];
      const float* wD = &wefs[75 + uy*5];
      p0a = fmaf(q0.x, wA[0], fmaf(q0.y, wB[0], p0a));
      p0b = fmaf(q0.x, wC[0], fmaf(q0.y, wD[0], p0b));
      p1a = fmaf(q0.z, wA[0], fmaf(q0.w, wB[0], p1a));
      p1b = fmaf(q0.z, wC[0], fmaf(q0.w, wD[0], p1b));
      p0a = fmaf(q0.z, wA[1], fmaf(q0.w, wB[1], p0a));
      p0b = fmaf(q0.z, wC[1], fmaf(q0.w, wD[1], p0b));
      p1a = fmaf(q1.x, wA[1], fmaf(q1.y, wB[1], p1a));
      p1b = fmaf(q1.x, wC[1], fmaf(q1.y, wD[1], p1b));
      p0a = fmaf(q1.x, wA[2], fmaf(q1.y, wB[2], p0a));
      p0b = fmaf(q1.x, wC[2], fmaf(q1.y, wD[2], p0b));
      p1a = fmaf(q1.z, wA[2], fmaf(q1.w, wB[2], p1a));
      p1b = fmaf(q1.z, wC[2], fmaf(q1.w, wD[2], p1b));
      p0a = fmaf(q1.z, wA[3], fmaf(q1.w, wB[3], p0a));
      p0b = fmaf(q1.z, wC[3], fmaf(q1.w, wD[3], p0b));
      p1a = fmaf(q2.x, wA[3], fmaf(q2.y, wB[3], p1a));
      p1b = fmaf(q2.x, wC[3], fmaf(q2.y, wD[3], p1b));
      p0a = fmaf(q2.x, wA[4], fmaf(q2.y, wB[4], p0a));
      p0b = fmaf(q2.x, wC[4], fmaf(q2.y, wD[4], p0b));
      p1a = fmaf(q2.z, wA[4], fmaf(q2.w, wB[4], p1a));
      p1b = fmaf(q2.z, wC[4], fmaf(q2.w, wD[4], p1b));
    }
    if(yin){
      if(ox != 0 && ox != 254){
        *(float2*)(out + ob0 + ox) = make_float2(p0a, p1a);
        *(float2*)(out + ob1 + ox) = make_float2(p0b, p1b);
      } else if(ox == 0){
        out[ob0 + 1] = p1a; out[ob1 + 1] = p1b;
      } else { // ox == 254
        out[ob0 + 254] = p0a; out[ob1 + 254] = p0b;
      }
    }
  }

  // ---- border fixup: full recompute + G/Cb correction, all from strip LDS ----
  const int nb = 32 + ((y0 == 0) ? 254 : 0) + ((y0 == 240) ? 254 : 0);
  for(int idx = tid; idx < nb; idx += 256){
    int py2, ox2;
    if(idx < 32){ py2 = idx >> 1; ox2 = (idx & 1) ? 255 : 0; }
    else {
      int e = idx - 32;
      if(y0 == 0 && e < 254){ py2 = 0; ox2 = 1 + e; }
      else { if(y0 == 0) e -= 254; py2 = 15; ox2 = 1 + e; }
    }
    const int oy2 = y0 + py2;
    float a0 = wefs[100], a1 = wefs[101];
#pragma unroll
    for(int uy = 0; uy < 5; ++uy)
#pragma unroll
      for(int ux = 0; ux < 5; ++ux){
        const float2 v = strip[py2 + uy][ox2 + ux];
        const int wi = uy*5 + ux;
        a0 = fmaf(v.x, wefs[wi],      fmaf(v.y, wefs[25 + wi], a0));
        a1 = fmaf(v.x, wefs[50 + wi], fmaf(v.y, wefs[75 + wi], a1));
      }
    for(int dy = 0; dy < 3; ++dy)
      for(int dx = 0; dx < 3; ++dx){
        const int gy2 = oy2 + dy - 1, gx2 = ox2 + dx - 1;
        if((unsigned)gy2 < 256u && (unsigned)gx2 < 256u) continue;
        const int d = dy*3 + dx;
        float c0 = Cbs[d], c1 = Cbs[9 + d];
        for(int ky = 0; ky < 3; ++ky){
          const int sy = gy2 + ky - 1;
          if((unsigned)sy >= 256u) continue;
          const int sr2 = sy - y0 + 2;
          for(int kx = 0; kx < 3; ++kx){
            const int sx = gx2 + kx - 1;
            if((unsigned)sx >= 256u) continue;
            const float2 v = strip[sr2][2 + sx];
            const int k9 = ky*3 + kx;
            c0 += Gs[0*81 + d*9 + k9]*v.x + Gs[1*81 + d*9 + k9]*v.y;
            c1 += Gs[2*81 + d*9 + k9]*v.x + Gs[3*81 + d*9 + k9]*v.y;
          }
        }
        a0 -= c0; a1 -= c1;
      }
    out[((size_t)(b*2 + 0)*256 + oy2)*256 + ox2] = a0;
    out[((size_t)(b*2 + 1)*256 + oy2)*256 + ox2] = a1;
  }
}

extern "C" void kernel_launch(void* const* d_in, const int* in_sizes, int n_in,
                              void* d_out, int out_size, void* d_ws, size_t ws_size,
                              hipStream_t stream) {
  const float* tgt = (const float*)d_in[0];
  const float* ref = (const float*)d_in[1];
  const float* w1  = (const float*)d_in[2];
  const float* b1  = (const float*)d_in[3];
  const float* w2  = (const float*)d_in[4];
  const float* b2  = (const float*)d_in[5];
  float* out = (float*)d_out;

  // ws: dkwT @0 (5.84MB), dkwC @8MB (5.84MB), wbuf @16MB (444 f32)
  float2* dkwT = (float2*)d_ws;
  float2* dkwC = (float2*)((char*)d_ws + (size_t)8*1024*1024);
  float*  wbuf = (float*)((char*)d_ws + (size_t)16*1024*1024);

  k_rowfft<<<513, 256, 0, stream>>>(tgt, ref, dkwT, w1, b1, w2, b2, wbuf);
  dim3 gc(12, 32);
  k_colfft<<<gc, 512, 0, stream>>>(dkwT, dkwC);
  dim3 gs(16, 32);
  k_strip <<<gs, 256, 0, stream>>>(dkwC, ref, wbuf, out);
}

// Round 9
// 102.336 us; speedup vs baseline: 1.2282x; 1.1471x over previous
//
#include <hip/hip_runtime.h>

#define PI_F 3.14159265358979323846f
#define SC (1.0f/65536.0f)

typedef unsigned u32x2 __attribute__((ext_vector_type(2)));

__device__ __forceinline__ float2 cmul(float2 a, float2 b){
  return make_float2(fmaf(a.x, b.x, -(a.y*b.y)), fmaf(a.x, b.y, a.y*b.x));
}
__device__ __forceinline__ float2 cadd(float2 a, float2 b){ return make_float2(a.x+b.x, a.y+b.y); }
__device__ __forceinline__ float2 csub(float2 a, float2 b){ return make_float2(a.x-b.x, a.y-b.y); }

// 6-bit reversal of lane id (radix-2 DIF output order)
__device__ __forceinline__ int rev2(int l){
  return ((l&1)<<5)|((l&2)<<3)|((l&4)<<1)|((l&8)>>1)|((l&16)>>3)|((l&32)>>5);
}

template<int SIGN>
__device__ __forceinline__ float2 twf(float th){
  float sn, cs; __sincosf(th, &sn, &cs);
  return make_float2(cs, (SIGN<0)? -sn : sn);
}

// ---- lane-exchange primitives (VALU/DPP where possible, DS only for stride 4/16) ----
template<int CTRL>
__device__ __forceinline__ float2 dppx(float2 v){
  float2 r;
  r.x = __int_as_float(__builtin_amdgcn_update_dpp(0, __float_as_int(v.x), CTRL, 0xF, 0xF, false));
  r.y = __int_as_float(__builtin_amdgcn_update_dpp(0, __float_as_int(v.y), CTRL, 0xF, 0xF, false));
  return r;
}
template<int OFF>
__device__ __forceinline__ float2 swzx(float2 v){
  float2 r;
  r.x = __int_as_float(__builtin_amdgcn_ds_swizzle(__float_as_int(v.x), OFF));
  r.y = __int_as_float(__builtin_amdgcn_ds_swizzle(__float_as_int(v.y), OFF));
  return r;
}
// stride-32: lo = v[l&31], hi = v[l|32] for every lane
__device__ __forceinline__ void x32(float2 v, int l, float2& lo, float2& hi){
#if __has_builtin(__builtin_amdgcn_permlane32_swap)
  u32x2 rx = __builtin_amdgcn_permlane32_swap(__float_as_uint(v.x), __float_as_uint(v.x), false, false);
  u32x2 ry = __builtin_amdgcn_permlane32_swap(__float_as_uint(v.y), __float_as_uint(v.y), false, false);
  lo = make_float2(__uint_as_float(rx[0]), __uint_as_float(ry[0]));
  hi = make_float2(__uint_as_float(rx[1]), __uint_as_float(ry[1]));
#else
  float2 p = make_float2(__shfl(v.x, l^32, 64), __shfl(v.y, l^32, 64));
  lo = (l&32) ? p : v;
  hi = (l&32) ? v : p;
#endif
}

// per-lane stage constants: sg[i] = (l & (32>>i)) ? -1 : +1 (i=0..5, m=32..1);
// tw[i] (i=0..4, m=32..2): (l&m) ? e^{SIGN*2pi*i*(l&(m-1))/(2m)} : 1. m=1 has no twiddle.
template<int SIGN>
__device__ __forceinline__ void mk_tw(int l, float2 tw[5], float sg[6]){
#pragma unroll
  for(int i=0;i<6;++i){ const int m = 32>>i; sg[i] = (l&m)? -1.f : 1.f; }
#pragma unroll
  for(int i=0;i<5;++i){
    const int m = 32>>i;
    const int j = l & (m-1);
    float2 w = twf<SIGN>((2.0f*PI_F)*(float)j/(float)(2*m));
    tw[i] = (l&m) ? w : make_float2(1.f, 0.f);
  }
}

// forward 64-pt DFT across lanes (radix-2 DIF): in v[l] -> out S[rev2(l)] at lane l.
__device__ __forceinline__ float2 fladder(float2 d, int l, const float2 tw[5], const float sg[6]){
  float2 lo, hi, t, p;
  x32(d, l, lo, hi);                                  // m=32
  t.x = fmaf(sg[0], hi.x, lo.x); t.y = fmaf(sg[0], hi.y, lo.y);
  d = cmul(t, tw[0]);
  p = swzx<0x401F>(d);                                // m=16 (xor 16)
  t.x = fmaf(sg[1], d.x, p.x);  t.y = fmaf(sg[1], d.y, p.y);
  d = cmul(t, tw[1]);
  p = dppx<0x128>(d);                                 // m=8 (row_ror:8 == xor 8)
  t.x = fmaf(sg[2], d.x, p.x);  t.y = fmaf(sg[2], d.y, p.y);
  d = cmul(t, tw[2]);
  p = swzx<0x101F>(d);                                // m=4 (xor 4)
  t.x = fmaf(sg[3], d.x, p.x);  t.y = fmaf(sg[3], d.y, p.y);
  d = cmul(t, tw[3]);
  p = dppx<0x4E>(d);                                  // m=2 (quad_perm xor 2)
  t.x = fmaf(sg[4], d.x, p.x);  t.y = fmaf(sg[4], d.y, p.y);
  d = cmul(t, tw[4]);
  p = dppx<0xB1>(d);                                  // m=1 (quad_perm xor 1), no twiddle
  d.x = fmaf(sg[5], d.x, p.x);  d.y = fmaf(sg[5], d.y, p.y);
  return d;
}

// inverse 64-pt DFT across lanes (radix-2 DIT): in Y[rev2(l)] at lane l -> out y[l].
__device__ __forceinline__ float2 iladder(float2 d, int l, const float2 tw[5], const float sg[6]){
  float2 p, t, lo, hi;
  p = dppx<0xB1>(d);                                  // m=1, no twiddle
  t.x = fmaf(sg[5], d.x, p.x);  t.y = fmaf(sg[5], d.y, p.y); d = t;
  d = cmul(d, tw[4]);                                 // m=2
  p = dppx<0x4E>(d);
  t.x = fmaf(sg[4], d.x, p.x);  t.y = fmaf(sg[4], d.y, p.y); d = t;
  d = cmul(d, tw[3]);                                 // m=4
  p = swzx<0x101F>(d);
  t.x = fmaf(sg[3], d.x, p.x);  t.y = fmaf(sg[3], d.y, p.y); d = t;
  d = cmul(d, tw[2]);                                 // m=8
  p = dppx<0x128>(d);
  t.x = fmaf(sg[2], d.x, p.x);  t.y = fmaf(sg[2], d.y, p.y); d = t;
  d = cmul(d, tw[1]);                                 // m=16
  p = swzx<0x401F>(d);
  t.x = fmaf(sg[1], d.x, p.x);  t.y = fmaf(sg[1], d.y, p.y); d = t;
  d = cmul(d, tw[0]);                                 // m=32
  x32(d, l, lo, hi);
  d.x = fmaf(sg[0], hi.x, lo.x); d.y = fmaf(sg[0], hi.y, lo.y);
  return d;
}

// fwd3: input d[p] = x[4l+p] -> output d[k0] = X[rev2(l) + 64*k0]. Unnormalized.
__device__ __forceinline__ void fwd3(float2 d[4], int l, int r4,
                                     const float2 tw[5], const float sg[6]){
#pragma unroll
  for(int p=0;p<4;++p) d[p] = fladder(d[p], l, tw, sg);
  float2 w1 = twf<-1>((2.0f*PI_F/256.0f)*(float)r4);
  float2 w2 = cmul(w1,w1), w3 = cmul(w2,w1);
  d[1]=cmul(d[1],w1); d[2]=cmul(d[2],w2); d[3]=cmul(d[3],w3);
  float2 e=cadd(d[0],d[2]), f=csub(d[0],d[2]), g=cadd(d[1],d[3]), h=csub(d[1],d[3]);
  float2 mih = make_float2(h.y, -h.x);
  d[0]=cadd(e,g); d[1]=cadd(f,mih); d[2]=csub(e,g); d[3]=csub(f,mih);
}

// inv3: input d[k0] = Y[rev2(l) + 64*k0] -> output d[p] = z[4l+p]. Unnormalized.
__device__ __forceinline__ void inv3(float2 d[4], int l, int r4,
                                     const float2 tw[5], const float sg[6]){
  {
    float2 e=cadd(d[0],d[2]), f=csub(d[0],d[2]), g=cadd(d[1],d[3]), h=csub(d[1],d[3]);
    float2 pih = make_float2(-h.y, h.x);
    d[0]=cadd(e,g); d[1]=cadd(f,pih); d[2]=csub(e,g); d[3]=csub(f,pih);
  }
  float2 w1 = twf<1>((2.0f*PI_F/256.0f)*(float)r4);
  float2 w2 = cmul(w1,w1), w3 = cmul(w2,w1);
  d[1]=cmul(d[1],w1); d[2]=cmul(d[2],w2); d[3]=cmul(d[3],w3);
#pragma unroll
  for(int p=0;p<4;++p) d[p] = iladder(d[p], l, tw, sg);
}

// kept k = r4 + 64*k0: k0==0 kept iff r4<44 (compact c=r4); k0==3 kept iff r4>=19 (c=25+r4).

// K1: block = (batch, 16 rows). d=tgt-ref, fwd3 per row (float4 loads, next-row prefetch),
//     kept coeffs -> padded LDS -> coalesced dkwT[b][c][h]. Block 512: composite weights.
__global__ __launch_bounds__(256) void k_rowfft(const float* __restrict__ tgt,
                                                const float* __restrict__ ref,
                                                float2* __restrict__ dkwT,
                                                const float* __restrict__ w1g,
                                                const float* __restrict__ b1g,
                                                const float* __restrict__ w2g,
                                                const float* __restrict__ b2g,
                                                float* __restrict__ wbuf){
  __shared__ __align__(16) float2 cT[89][17];
  const int tid = threadIdx.x;
  if(blockIdx.x == 512){
    float* wsh = (float*)cT;
    float* w1s = wsh;
    float* w2s = wsh + 1152;
    float* b1s = wsh + 2304;
    float* b2s = wsh + 2368;
    for(int t = tid; t < 1152; t += 256){ w1s[t] = w1g[t]; w2s[t] = w2g[t]; }
    if(tid < 64) b1s[tid] = b1g[tid];
    if(tid < 2)  b2s[tid] = b2g[tid];
    __syncthreads();
    for(int t = tid; t < 444; t += 256){
      if(t < 100){
        const int ux = t % 5, uy = (t/5) % 5, ic = (t/25) & 1, oc = t/50;
        float acc = 0.f;
        for(int mc = 0; mc < 64; ++mc)
          for(int dy = 0; dy < 3; ++dy){
            int ky = uy - dy; if((unsigned)ky >= 3u) continue;
            for(int dx = 0; dx < 3; ++dx){
              int kx = ux - dx; if((unsigned)kx >= 3u) continue;
              acc = fmaf(w2s[((oc*64+mc)*3+dy)*3+dx], w1s[((mc*2+ic)*3+ky)*3+kx], acc);
            }
          }
        wbuf[t] = acc;
      } else if(t < 102){
        const int oc = t - 100;
        float acc = b2s[oc];
        for(int mc = 0; mc < 64; ++mc){
          float s = 0.f;
          for(int d = 0; d < 9; ++d) s += w2s[(oc*64+mc)*9 + d];
          acc = fmaf(s, b1s[mc], acc);
        }
        wbuf[t] = acc;
      } else if(t < 426){
        const int g = t - 102;
        const int oc = g / 162, r1 = g - oc*162;
        const int ic = r1 / 81,  r2 = r1 - ic*81;
        const int d  = r2 / 9,   k9 = r2 - d*9;
        float acc = 0.f;
        for(int mc = 0; mc < 64; ++mc)
          acc = fmaf(w2s[(oc*64+mc)*9 + d], w1s[(mc*2+ic)*9 + k9], acc);
        wbuf[t] = acc;
      } else {
        const int i = t - 426, oc = i / 9, d = i - oc*9;
        float acc = 0.f;
        for(int mc = 0; mc < 64; ++mc)
          acc = fmaf(w2s[(oc*64+mc)*9 + d], b1s[mc], acc);
        wbuf[t] = acc;
      }
    }
    return;
  }
  const int wv = tid >> 6, ln = tid & 63, r4 = rev2(ln);
  float2 twF[5]; float sg[6];
  mk_tw<-1>(ln, twF, sg);
  const int b  = blockIdx.x >> 4;
  const int h0 = (blockIdx.x & 15) << 4;
  const float* t0p = tgt + (size_t)(b*2 + 0)*65536;
  const float* t1p = tgt + (size_t)(b*2 + 1)*65536;
  const float* r0p = ref + (size_t)(b*2 + 0)*65536;
  const float* r1p = ref + (size_t)(b*2 + 1)*65536;

  int h = h0 + wv*4;
  float4 c0 = *(const float4*)(t0p + h*256 + 4*ln);
  float4 c1 = *(const float4*)(t1p + h*256 + 4*ln);
  float4 c2 = *(const float4*)(r0p + h*256 + 4*ln);
  float4 c3 = *(const float4*)(r1p + h*256 + 4*ln);
#pragma unroll
  for(int i = 0; i < 4; ++i){
    float4 n0, n1, n2, n3;
    if(i < 3){
      const int h2 = h + 1;
      n0 = *(const float4*)(t0p + h2*256 + 4*ln);
      n1 = *(const float4*)(t1p + h2*256 + 4*ln);
      n2 = *(const float4*)(r0p + h2*256 + 4*ln);
      n3 = *(const float4*)(r1p + h2*256 + 4*ln);
    }
    float2 d[4];
    d[0] = make_float2(c0.x - c2.x, c1.x - c3.x);
    d[1] = make_float2(c0.y - c2.y, c1.y - c3.y);
    d[2] = make_float2(c0.z - c2.z, c1.z - c3.z);
    d[3] = make_float2(c0.w - c2.w, c1.w - c3.w);
    fwd3(d, ln, r4, twF, sg);
    const int hh = wv*4 + i;
    if(r4 < 44)  cT[r4][hh]      = d[0];
    if(r4 >= 19) cT[25 + r4][hh] = d[3];
    c0 = n0; c1 = n1; c2 = n2; c3 = n3;
    ++h;
  }
  __syncthreads();
  for(int idx = tid; idx < 1424; idx += 256){
    const int c = idx >> 4, hh = idx & 15;
    dkwT[(size_t)(b*89 + c)*256 + h0 + hh] = cT[c][hh];
  }
}

// K2: block = (batch, 8 columns), 512 thr (wave per column). fwd3 along h, mask, inv3.
__global__ __launch_bounds__(512) void k_colfft(const float2* __restrict__ dkwT,
                                                float2* __restrict__ dkwC){
  __shared__ __align__(16) float2 sT[8][256];
  const int tid = threadIdx.x, wv = tid >> 6, ln = tid & 63, r4 = rev2(ln);
  float2 twF[5], twI[5]; float sg[6];
  mk_tw<-1>(ln, twF, sg);
  mk_tw< 1>(ln, twI, sg);
  const int b  = blockIdx.y;
  const int c0 = blockIdx.x * 8;
  const int c  = c0 + wv;
  if(c < 89){
    const float2* src = dkwT + (size_t)(b*89 + c)*256;
    const float4* s4 = (const float4*)(src + 4*ln);
    float4 p0 = s4[0], p1 = s4[1];
    float2 d[4];
    d[0] = make_float2(p0.x, p0.y);
    d[1] = make_float2(p0.z, p0.w);
    d[2] = make_float2(p1.x, p1.y);
    d[3] = make_float2(p1.z, p1.w);
    fwd3(d, ln, r4, twF, sg);
    if(r4 >= 44) d[0] = make_float2(0.f, 0.f);
    d[1] = make_float2(0.f, 0.f);
    d[2] = make_float2(0.f, 0.f);
    if(r4 < 19) d[3] = make_float2(0.f, 0.f);
    inv3(d, ln, r4, twI, sg);
    float4* o4 = (float4*)&sT[wv][4*ln];
    o4[0] = make_float4(d[0].x, d[0].y, d[1].x, d[1].y);
    o4[1] = make_float4(d[2].x, d[2].y, d[3].x, d[3].y);
  }
  __syncthreads();
#pragma unroll
  for(int t = 0; t < 4; ++t){
    const int idx = tid + 512*t;
    const int hh = idx >> 3, cw = idx & 7;
    if(c0 + cw < 89)
      dkwC[((size_t)b*256 + hh)*89 + c0 + cw] = sT[cw][hh];
  }
}

// K3: per 16-row strip: register row-IFFT of 20 rows into LDS (+refer), next-row prefetch,
//     ONE barrier, composite 5x5 conv, self-contained border fixup.
__global__ __launch_bounds__(256) void k_strip(const float2* __restrict__ dkwC,
                                               const float* __restrict__ ref,
                                               const float* __restrict__ wb,
                                               float* __restrict__ out){
  __shared__ __align__(16) float2 strip[20][264];
  __shared__ float wefs[102];
  __shared__ float Gs[324];
  __shared__ float Cbs[18];
  const int tid = threadIdx.x, wv = tid >> 6, ln = tid & 63, r4 = rev2(ln);
  float2 twI[5]; float sg[6];
  mk_tw<1>(ln, twI, sg);
  const int b = blockIdx.y, y0 = blockIdx.x * 16;

  for(int i = tid; i < 444; i += 256){
    float v = wb[i];
    if(i < 102) wefs[i] = v;
    else if(i < 426) Gs[i - 102] = v;
    else Cbs[i - 426] = v;
  }

  const float* rf0 = ref + (size_t)(b*2 + 0)*65536;
  const float* rf1 = ref + (size_t)(b*2 + 1)*65536;
  const float2 z2 = make_float2(0.f, 0.f);
  const float4 z4 = make_float4(0.f, 0.f, 0.f, 0.f);

  float4 pr0, pr1; float2 pd0, pd3;
  {
    const int gy = y0 - 2 + wv*5;
    const bool gv = ((unsigned)gy < 256u);
    const float2* row = dkwC + ((size_t)b*256 + (gv ? gy : 0))*89;
    pd0 = (gv && r4 < 44)  ? row[r4]      : z2;
    pd3 = (gv && r4 >= 19) ? row[25 + r4] : z2;
    pr0 = gv ? *(const float4*)(rf0 + gy*256 + 4*ln) : z4;
    pr1 = gv ? *(const float4*)(rf1 + gy*256 + 4*ln) : z4;
  }
#pragma unroll
  for(int i = 0; i < 5; ++i){
    float4 r0 = pr0, r1 = pr1;
    float2 d[4]; d[0] = pd0; d[1] = z2; d[2] = z2; d[3] = pd3;
    if(i < 4){
      const int gy2 = y0 - 2 + wv*5 + i + 1;
      const bool gv2 = ((unsigned)gy2 < 256u);
      const float2* row2 = dkwC + ((size_t)b*256 + (gv2 ? gy2 : 0))*89;
      pd0 = (gv2 && r4 < 44)  ? row2[r4]      : z2;
      pd3 = (gv2 && r4 >= 19) ? row2[25 + r4] : z2;
      pr0 = gv2 ? *(const float4*)(rf0 + gy2*256 + 4*ln) : z4;
      pr1 = gv2 ? *(const float4*)(rf1 + gy2*256 + 4*ln) : z4;
    }
    inv3(d, ln, r4, twI, sg);
    const int sr = wv*5 + i;
    float4* w4 = (float4*)&strip[sr][2 + 4*ln];
    w4[0] = make_float4(fmaf(d[0].x, SC, r0.x), fmaf(d[0].y, SC, r1.x),
                        fmaf(d[1].x, SC, r0.y), fmaf(d[1].y, SC, r1.y));
    w4[1] = make_float4(fmaf(d[2].x, SC, r0.z), fmaf(d[2].y, SC, r1.z),
                        fmaf(d[3].x, SC, r0.w), fmaf(d[3].y, SC, r1.w));
    if(ln < 2){
      strip[sr][ln] = z2;
      strip[sr][258 + ln] = z2;
    }
  }
  __syncthreads();

  const int rr_ = tid >> 4;
  const int pp  = tid & 15;
  const int oy  = y0 + rr_;
  const bool yin = (oy != 0) && (oy != 255);
  const size_t ob0 = ((size_t)(b*2 + 0)*256 + oy)*256;
  const size_t ob1 = ((size_t)(b*2 + 1)*256 + oy)*256;
#pragma unroll
  for(int j = 0; j < 8; ++j){
    const int ox = 2*pp + 32*j;
    float p0a = wefs[100], p0b = wefs[101];
    float p1a = p0a,       p1b = p0b;
#pragma unroll
    for(int uy = 0; uy < 5; ++uy){
      const float4* rp = (const float4*)&strip[rr_ + uy][ox];
      const float4 q0 = rp[0], q1 = rp[1], q2 = rp[2];
      const float* wA = &wefs[uy*5];
      const float* wB = &wefs[25 + uy*5];
      const float* wC = &wefs[50 + uy*5];
      const float* wD = &wefs[75 + uy*5];
      p0a = fmaf(q0.x, wA[0], fmaf(q0.y, wB[0], p0a));
      p0b = fmaf(q0.x, wC[0], fmaf(q0.y, wD[0], p0b));
      p1a = fmaf(q0.z, wA[0], fmaf(q0.w, wB[0], p1a));
      p1b = fmaf(q0.z, wC[0], fmaf(q0.w, wD[0], p1b));
      p0a = fmaf(q0.z, wA[1], fmaf(q0.w, wB[1], p0a));
      p0b = fmaf(q0.z, wC[1], fmaf(q0.w, wD[1], p0b));
      p1a = fmaf(q1.x, wA[1], fmaf(q1.y, wB[1], p1a));
      p1b = fmaf(q1.x, wC[1], fmaf(q1.y, wD[1], p1b));
      p0a = fmaf(q1.x, wA[2], fmaf(q1.y, wB[2], p0a));
      p0b = fmaf(q1.x, wC[2], fmaf(q1.y, wD[2], p0b));
      p1a = fmaf(q1.z, wA[2], fmaf(q1.w, wB[2], p1a));
      p1b = fmaf(q1.z, wC[2], fmaf(q1.w, wD[2], p1b));
      p0a = fmaf(q1.z, wA[3], fmaf(q1.w, wB[3], p0a));
      p0b = fmaf(q1.z, wC[3], fmaf(q1.w, wD[3], p0b));
      p1a = fmaf(q2.x, wA[3], fmaf(q2.y, wB[3], p1a));
      p1b = fmaf(q2.x, wC[3], fmaf(q2.y, wD[3], p1b));
      p0a = fmaf(q2.x, wA[4], fmaf(q2.y, wB[4], p0a));
      p0b = fmaf(q2.x, wC[4], fmaf(q2.y, wD[4], p0b));
      p1a = fmaf(q2.z, wA[4], fmaf(q2.w, wB[4], p1a));
      p1b = fmaf(q2.z, wC[4], fmaf(q2.w, wD[4], p1b));
    }
    if(yin){
      if(ox != 0 && ox != 254){
        *(float2*)(out + ob0 + ox) = make_float2(p0a, p1a);
        *(float2*)(out + ob1 + ox) = make_float2(p0b, p1b);
      } else if(ox == 0){
        out[ob0 + 1] = p1a; out[ob1 + 1] = p1b;
      } else {
        out[ob0 + 254] = p0a; out[ob1 + 254] = p0b;
      }
    }
  }

  const int nb = 32 + ((y0 == 0) ? 254 : 0) + ((y0 == 240) ? 254 : 0);
  for(int idx = tid; idx < nb; idx += 256){
    int py2, ox2;
    if(idx < 32){ py2 = idx >> 1; ox2 = (idx & 1) ? 255 : 0; }
    else {
      int e = idx - 32;
      if(y0 == 0 && e < 254){ py2 = 0; ox2 = 1 + e; }
      else { if(y0 == 0) e -= 254; py2 = 15; ox2 = 1 + e; }
    }
    const int oy2 = y0 + py2;
    float a0 = wefs[100], a1 = wefs[101];
#pragma unroll
    for(int uy = 0; uy < 5; ++uy)
#pragma unroll
      for(int ux = 0; ux < 5; ++ux){
        const float2 v = strip[py2 + uy][ox2 + ux];
        const int wi = uy*5 + ux;
        a0 = fmaf(v.x, wefs[wi],      fmaf(v.y, wefs[25 + wi], a0));
        a1 = fmaf(v.x, wefs[50 + wi], fmaf(v.y, wefs[75 + wi], a1));
      }
    for(int dy = 0; dy < 3; ++dy)
      for(int dx = 0; dx < 3; ++dx){
        const int gy2 = oy2 + dy - 1, gx2 = ox2 + dx - 1;
        if((unsigned)gy2 < 256u && (unsigned)gx2 < 256u) continue;
        const int d = dy*3 + dx;
        float c0 = Cbs[d], c1 = Cbs[9 + d];
        for(int ky = 0; ky < 3; ++ky){
          const int sy = gy2 + ky - 1;
          if((unsigned)sy >= 256u) continue;
          const int sr2 = sy - y0 + 2;
          for(int kx = 0; kx < 3; ++kx){
            const int sx = gx2 + kx - 1;
            if((unsigned)sx >= 256u) continue;
            const float2 v = strip[sr2][2 + sx];
            const int k9 = ky*3 + kx;
            c0 += Gs[0*81 + d*9 + k9]*v.x + Gs[1*81 + d*9 + k9]*v.y;
            c1 += Gs[2*81 + d*9 + k9]*v.x + Gs[3*81 + d*9 + k9]*v.y;
          }
        }
        a0 -= c0; a1 -= c1;
      }
    out[((size_t)(b*2 + 0)*256 + oy2)*256 + ox2] = a0;
    out[((size_t)(b*2 + 1)*256 + oy2)*256 + ox2] = a1;
  }
}

extern "C" void kernel_launch(void* const* d_in, const int* in_sizes, int n_in,
                              void* d_out, int out_size, void* d_ws, size_t ws_size,
                              hipStream_t stream) {
  const float* tgt = (const float*)d_in[0];
  const float* ref = (const float*)d_in[1];
  const float* w1  = (const float*)d_in[2];
  const float* b1  = (const float*)d_in[3];
  const float* w2  = (const float*)d_in[4];
  const float* b2  = (const float*)d_in[5];
  float* out = (float*)d_out;

  float2* dkwT = (float2*)d_ws;
  float2* dkwC = (float2*)((char*)d_ws + (size_t)8*1024*1024);
  float*  wbuf = (float*)((char*)d_ws + (size_t)16*1024*1024);

  k_rowfft<<<513, 256, 0, stream>>>(tgt, ref, dkwT, w1, b1, w2, b2, wbuf);
  dim3 gc(12, 32);
  k_colfft<<<gc, 512, 0, stream>>>(dkwT, dkwC);
  dim3 gs(16, 32);
  k_strip <<<gs, 256, 0, stream>>>(dkwC, ref, wbuf, out);
}

// Round 10
// 82.689 us; speedup vs baseline: 1.5200x; 1.2376x over previous
//
#include <hip/hip_runtime.h>

#define PI_F 3.14159265358979323846f
#define SC (1.0f/65536.0f)

typedef unsigned u32x2 __attribute__((ext_vector_type(2)));

__device__ __forceinline__ float2 cmul(float2 a, float2 b){
  return make_float2(fmaf(a.x, b.x, -(a.y*b.y)), fmaf(a.x, b.y, a.y*b.x));
}
__device__ __forceinline__ float2 cadd(float2 a, float2 b){ return make_float2(a.x+b.x, a.y+b.y); }
__device__ __forceinline__ float2 csub(float2 a, float2 b){ return make_float2(a.x-b.x, a.y-b.y); }

// 6-bit reversal of lane id (radix-2 DIF output order)
__device__ __forceinline__ int rev2(int l){
  return ((l&1)<<5)|((l&2)<<3)|((l&4)<<1)|((l&8)>>1)|((l&16)>>3)|((l&32)>>5);
}

template<int SIGN>
__device__ __forceinline__ float2 twf(float th){
  float sn, cs; __sincosf(th, &sn, &cs);
  return make_float2(cs, (SIGN<0)? -sn : sn);
}

// fp32 -> bf16, RNE
__device__ __forceinline__ unsigned short f2bf(float f){
  unsigned u = __float_as_uint(f);
  return (unsigned short)((u + 0x7FFFu + ((u >> 16) & 1u)) >> 16);
}
__device__ __forceinline__ float bf2f(unsigned short h){
  return __uint_as_float(((unsigned)h) << 16);
}

// ---- lane-exchange primitives ----
template<int CTRL>
__device__ __forceinline__ float2 dppx(float2 v){
  float2 r;
  r.x = __int_as_float(__builtin_amdgcn_update_dpp(0, __float_as_int(v.x), CTRL, 0xF, 0xF, false));
  r.y = __int_as_float(__builtin_amdgcn_update_dpp(0, __float_as_int(v.y), CTRL, 0xF, 0xF, false));
  return r;
}
template<int OFF>
__device__ __forceinline__ float2 swzx(float2 v){
  float2 r;
  r.x = __int_as_float(__builtin_amdgcn_ds_swizzle(__float_as_int(v.x), OFF));
  r.y = __int_as_float(__builtin_amdgcn_ds_swizzle(__float_as_int(v.y), OFF));
  return r;
}
__device__ __forceinline__ void x32(float2 v, int l, float2& lo, float2& hi){
#if __has_builtin(__builtin_amdgcn_permlane32_swap)
  u32x2 rx = __builtin_amdgcn_permlane32_swap(__float_as_uint(v.x), __float_as_uint(v.x), false, false);
  u32x2 ry = __builtin_amdgcn_permlane32_swap(__float_as_uint(v.y), __float_as_uint(v.y), false, false);
  lo = make_float2(__uint_as_float(rx[0]), __uint_as_float(ry[0]));
  hi = make_float2(__uint_as_float(rx[1]), __uint_as_float(ry[1]));
#else
  float2 p = make_float2(__shfl(v.x, l^32, 64), __shfl(v.y, l^32, 64));
  lo = (l&32) ? p : v;
  hi = (l&32) ? v : p;
#endif
}

template<int SIGN>
__device__ __forceinline__ void mk_tw(int l, float2 tw[5], float sg[6]){
#pragma unroll
  for(int i=0;i<6;++i){ const int m = 32>>i; sg[i] = (l&m)? -1.f : 1.f; }
#pragma unroll
  for(int i=0;i<5;++i){
    const int m = 32>>i;
    const int j = l & (m-1);
    float2 w = twf<SIGN>((2.0f*PI_F)*(float)j/(float)(2*m));
    tw[i] = (l&m) ? w : make_float2(1.f, 0.f);
  }
}

// forward 64-pt DFT across lanes (radix-2 DIF): in v[l] -> out S[rev2(l)] at lane l.
__device__ __forceinline__ float2 fladder(float2 d, int l, const float2 tw[5], const float sg[6]){
  float2 lo, hi, t, p;
  x32(d, l, lo, hi);
  t.x = fmaf(sg[0], hi.x, lo.x); t.y = fmaf(sg[0], hi.y, lo.y);
  d = cmul(t, tw[0]);
  p = swzx<0x401F>(d);
  t.x = fmaf(sg[1], d.x, p.x);  t.y = fmaf(sg[1], d.y, p.y);
  d = cmul(t, tw[1]);
  p = dppx<0x128>(d);
  t.x = fmaf(sg[2], d.x, p.x);  t.y = fmaf(sg[2], d.y, p.y);
  d = cmul(t, tw[2]);
  p = swzx<0x101F>(d);
  t.x = fmaf(sg[3], d.x, p.x);  t.y = fmaf(sg[3], d.y, p.y);
  d = cmul(t, tw[3]);
  p = dppx<0x4E>(d);
  t.x = fmaf(sg[4], d.x, p.x);  t.y = fmaf(sg[4], d.y, p.y);
  d = cmul(t, tw[4]);
  p = dppx<0xB1>(d);
  d.x = fmaf(sg[5], d.x, p.x);  d.y = fmaf(sg[5], d.y, p.y);
  return d;
}

// inverse 64-pt DFT across lanes (radix-2 DIT): in Y[rev2(l)] at lane l -> out y[l].
__device__ __forceinline__ float2 iladder(float2 d, int l, const float2 tw[5], const float sg[6]){
  float2 p, t, lo, hi;
  p = dppx<0xB1>(d);
  t.x = fmaf(sg[5], d.x, p.x);  t.y = fmaf(sg[5], d.y, p.y); d = t;
  d = cmul(d, tw[4]);
  p = dppx<0x4E>(d);
  t.x = fmaf(sg[4], d.x, p.x);  t.y = fmaf(sg[4], d.y, p.y); d = t;
  d = cmul(d, tw[3]);
  p = swzx<0x101F>(d);
  t.x = fmaf(sg[3], d.x, p.x);  t.y = fmaf(sg[3], d.y, p.y); d = t;
  d = cmul(d, tw[2]);
  p = dppx<0x128>(d);
  t.x = fmaf(sg[2], d.x, p.x);  t.y = fmaf(sg[2], d.y, p.y); d = t;
  d = cmul(d, tw[1]);
  p = swzx<0x401F>(d);
  t.x = fmaf(sg[1], d.x, p.x);  t.y = fmaf(sg[1], d.y, p.y); d = t;
  d = cmul(d, tw[0]);
  x32(d, l, lo, hi);
  d.x = fmaf(sg[0], hi.x, lo.x); d.y = fmaf(sg[0], hi.y, lo.y);
  return d;
}

// fwd3: input d[p] = x[4l+p] -> output d[k0] = X[rev2(l) + 64*k0]. Unnormalized.
__device__ __forceinline__ void fwd3(float2 d[4], int l, int r4,
                                     const float2 tw[5], const float sg[6]){
#pragma unroll
  for(int p=0;p<4;++p) d[p] = fladder(d[p], l, tw, sg);
  float2 w1 = twf<-1>((2.0f*PI_F/256.0f)*(float)r4);
  float2 w2 = cmul(w1,w1), w3 = cmul(w2,w1);
  d[1]=cmul(d[1],w1); d[2]=cmul(d[2],w2); d[3]=cmul(d[3],w3);
  float2 e=cadd(d[0],d[2]), f=csub(d[0],d[2]), g=cadd(d[1],d[3]), h=csub(d[1],d[3]);
  float2 mih = make_float2(h.y, -h.x);
  d[0]=cadd(e,g); d[1]=cadd(f,mih); d[2]=csub(e,g); d[3]=csub(f,mih);
}

// inv3: input d[k0] = Y[rev2(l) + 64*k0] -> output d[p] = z[4l+p]. Unnormalized.
__device__ __forceinline__ void inv3(float2 d[4], int l, int r4,
                                     const float2 tw[5], const float sg[6]){
  {
    float2 e=cadd(d[0],d[2]), f=csub(d[0],d[2]), g=cadd(d[1],d[3]), h=csub(d[1],d[3]);
    float2 pih = make_float2(-h.y, h.x);
    d[0]=cadd(e,g); d[1]=cadd(f,pih); d[2]=csub(e,g); d[3]=csub(f,pih);
  }
  float2 w1 = twf<1>((2.0f*PI_F/256.0f)*(float)r4);
  float2 w2 = cmul(w1,w1), w3 = cmul(w2,w1);
  d[1]=cmul(d[1],w1); d[2]=cmul(d[2],w2); d[3]=cmul(d[3],w3);
#pragma unroll
  for(int p=0;p<4;++p) d[p] = iladder(d[p], l, tw, sg);
}

// kept k = r4 + 64*k0: k0==0 kept iff r4<44 (c=r4); k0==3 kept iff r4>=19 (c=25+r4).

// K1: 1024 thr, wave = one line. d=tgt-ref, fwd3, kept coeffs -> cT -> dkwT[b][c][h].
//     Block 512: composite weights into wbuf.
__global__ __launch_bounds__(1024) void k_rowfft(const float* __restrict__ tgt,
                                                 const float* __restrict__ ref,
                                                 float2* __restrict__ dkwT,
                                                 const float* __restrict__ w1g,
                                                 const float* __restrict__ b1g,
                                                 const float* __restrict__ w2g,
                                                 const float* __restrict__ b2g,
                                                 float* __restrict__ wbuf){
  __shared__ __align__(16) float2 cT[89][17];
  const int tid = threadIdx.x;
  if(blockIdx.x == 512){
    float* wsh = (float*)cT;
    float* w1s = wsh;
    float* w2s = wsh + 1152;
    float* b1s = wsh + 2304;
    float* b2s = wsh + 2368;
    for(int t = tid; t < 1152; t += 1024){ w1s[t] = w1g[t]; w2s[t] = w2g[t]; }
    if(tid < 64) b1s[tid] = b1g[tid];
    if(tid >= 64 && tid < 66) b2s[tid-64] = b2g[tid-64];
    __syncthreads();
    for(int t = tid; t < 444; t += 1024){
      if(t < 100){
        const int ux = t % 5, uy = (t/5) % 5, ic = (t/25) & 1, oc = t/50;
        float acc = 0.f;
        for(int mc = 0; mc < 64; ++mc)
          for(int dy = 0; dy < 3; ++dy){
            int ky = uy - dy; if((unsigned)ky >= 3u) continue;
            for(int dx = 0; dx < 3; ++dx){
              int kx = ux - dx; if((unsigned)kx >= 3u) continue;
              acc = fmaf(w2s[((oc*64+mc)*3+dy)*3+dx], w1s[((mc*2+ic)*3+ky)*3+kx], acc);
            }
          }
        wbuf[t] = acc;
      } else if(t < 102){
        const int oc = t - 100;
        float acc = b2s[oc];
        for(int mc = 0; mc < 64; ++mc){
          float s = 0.f;
          for(int d = 0; d < 9; ++d) s += w2s[(oc*64+mc)*9 + d];
          acc = fmaf(s, b1s[mc], acc);
        }
        wbuf[t] = acc;
      } else if(t < 426){
        const int g = t - 102;
        const int oc = g / 162, r1 = g - oc*162;
        const int ic = r1 / 81,  r2 = r1 - ic*81;
        const int d  = r2 / 9,   k9 = r2 - d*9;
        float acc = 0.f;
        for(int mc = 0; mc < 64; ++mc)
          acc = fmaf(w2s[(oc*64+mc)*9 + d], w1s[(mc*2+ic)*9 + k9], acc);
        wbuf[t] = acc;
      } else {
        const int i = t - 426, oc = i / 9, d = i - oc*9;
        float acc = 0.f;
        for(int mc = 0; mc < 64; ++mc)
          acc = fmaf(w2s[(oc*64+mc)*9 + d], b1s[mc], acc);
        wbuf[t] = acc;
      }
    }
    return;
  }
  const int wv = tid >> 6, ln = tid & 63, r4 = rev2(ln);
  float2 twF[5]; float sg[6];
  mk_tw<-1>(ln, twF, sg);
  const int b  = blockIdx.x >> 4;
  const int h0 = (blockIdx.x & 15) << 4;
  const int h  = h0 + wv;
  const float4 c0 = *(const float4*)(tgt + ((size_t)(b*2+0)*256 + h)*256 + 4*ln);
  const float4 c1 = *(const float4*)(tgt + ((size_t)(b*2+1)*256 + h)*256 + 4*ln);
  const float4 c2 = *(const float4*)(ref + ((size_t)(b*2+0)*256 + h)*256 + 4*ln);
  const float4 c3 = *(const float4*)(ref + ((size_t)(b*2+1)*256 + h)*256 + 4*ln);
  float2 d[4];
  d[0] = make_float2(c0.x - c2.x, c1.x - c3.x);
  d[1] = make_float2(c0.y - c2.y, c1.y - c3.y);
  d[2] = make_float2(c0.z - c2.z, c1.z - c3.z);
  d[3] = make_float2(c0.w - c2.w, c1.w - c3.w);
  fwd3(d, ln, r4, twF, sg);
  if(r4 < 44)  cT[r4][wv]      = d[0];
  if(r4 >= 19) cT[25 + r4][wv] = d[3];
  __syncthreads();
  for(int idx = tid; idx < 1424; idx += 1024){
    const int c = idx >> 4, hh = idx & 15;
    dkwT[(size_t)(b*89 + c)*256 + h0 + hh] = cT[c][hh];
  }
}

// K2: block = (batch, 8 columns), 512 thr (wave per column). fwd3 along h, mask, inv3.
__global__ __launch_bounds__(512) void k_colfft(const float2* __restrict__ dkwT,
                                                float2* __restrict__ dkwC){
  __shared__ __align__(16) float2 sT[8][256];
  const int tid = threadIdx.x, wv = tid >> 6, ln = tid & 63, r4 = rev2(ln);
  float2 twF[5], twI[5]; float sg[6];
  mk_tw<-1>(ln, twF, sg);
  mk_tw< 1>(ln, twI, sg);
  const int b  = blockIdx.y;
  const int c0 = blockIdx.x * 8;
  const int c  = c0 + wv;
  if(c < 89){
    const float2* src = dkwT + (size_t)(b*89 + c)*256;
    const float4* s4 = (const float4*)(src + 4*ln);
    float4 p0 = s4[0], p1 = s4[1];
    float2 d[4];
    d[0] = make_float2(p0.x, p0.y);
    d[1] = make_float2(p0.z, p0.w);
    d[2] = make_float2(p1.x, p1.y);
    d[3] = make_float2(p1.z, p1.w);
    fwd3(d, ln, r4, twF, sg);
    if(r4 >= 44) d[0] = make_float2(0.f, 0.f);
    d[1] = make_float2(0.f, 0.f);
    d[2] = make_float2(0.f, 0.f);
    if(r4 < 19) d[3] = make_float2(0.f, 0.f);
    inv3(d, ln, r4, twI, sg);
    float4* o4 = (float4*)&sT[wv][4*ln];
    o4[0] = make_float4(d[0].x, d[0].y, d[1].x, d[1].y);
    o4[1] = make_float4(d[2].x, d[2].y, d[3].x, d[3].y);
  }
  __syncthreads();
#pragma unroll
  for(int t = 0; t < 4; ++t){
    const int idx = tid + 512*t;
    const int hh = idx >> 3, cw = idx & 7;
    if(c0 + cw < 89)
      dkwC[((size_t)b*256 + hh)*89 + c0 + cw] = sT[cw][hh];
  }
}

// K3: wave = one image row. Row-IFFT from dkwC, +refer, write bf16 into padded
//     chg buffer [b*2+ch][260 rows][264 cols] (row r = gy+2, data at col 4+x, pads zero).
__global__ __launch_bounds__(256) void k_ifft(const float2* __restrict__ dkwC,
                                              const float* __restrict__ ref,
                                              unsigned short* __restrict__ chgb){
  const int tid = threadIdx.x, wv = tid >> 6, ln = tid & 63;
  const int w = blockIdx.x*4 + wv;          // 0..8319 = b*260 + r
  const int b = w / 260;
  const int r = w - b*260;
  const int gy = r - 2;
  unsigned short* row0 = chgb + ((size_t)(b*2 + 0)*260 + r)*264;
  unsigned short* row1 = chgb + ((size_t)(b*2 + 1)*260 + r)*264;
  const ushort4 zu = make_ushort4(0,0,0,0);
  if((unsigned)gy >= 256u){
    *(ushort4*)(row0 + 4*ln) = zu;
    *(ushort4*)(row1 + 4*ln) = zu;
    if(ln < 2){
      *(ushort4*)(row0 + 256 + 4*ln) = zu;
      *(ushort4*)(row1 + 256 + 4*ln) = zu;
    }
    return;
  }
  const int r4 = rev2(ln);
  float2 twI[5]; float sg[6];
  mk_tw<1>(ln, twI, sg);
  const float2* row = dkwC + ((size_t)b*256 + gy)*89;
  const float2 z2 = make_float2(0.f, 0.f);
  float2 d[4];
  d[0] = (r4 < 44)  ? row[r4]      : z2;
  d[1] = z2; d[2] = z2;
  d[3] = (r4 >= 19) ? row[25 + r4] : z2;
  const float4 rr = *(const float4*)(ref + ((size_t)(b*2+0)*256 + gy)*256 + 4*ln);
  const float4 ri = *(const float4*)(ref + ((size_t)(b*2+1)*256 + gy)*256 + 4*ln);
  inv3(d, ln, r4, twI, sg);
  ushort4 o0, o1;
  o0.x = f2bf(fmaf(d[0].x, SC, rr.x)); o0.y = f2bf(fmaf(d[1].x, SC, rr.y));
  o0.z = f2bf(fmaf(d[2].x, SC, rr.z)); o0.w = f2bf(fmaf(d[3].x, SC, rr.w));
  o1.x = f2bf(fmaf(d[0].y, SC, ri.x)); o1.y = f2bf(fmaf(d[1].y, SC, ri.y));
  o1.z = f2bf(fmaf(d[2].y, SC, ri.z)); o1.w = f2bf(fmaf(d[3].y, SC, ri.w));
  *(ushort4*)(row0 + 4 + 4*ln) = o0;
  *(ushort4*)(row1 + 4 + 4*ln) = o1;
  if(ln == 0){
    *(ushort4*)(row0) = zu; *(ushort4*)(row1) = zu;
  } else if(ln == 1){
    *(ushort4*)(row0 + 260) = zu; *(ushort4*)(row1 + 260) = zu;
  }
}

// K4: thread = 4 output px of one row. 10 independent 16B bf16 loads (5 rows x 2 ch
//     covering x-2..x+5), 400 FMA composite 5x5 conv, G/Cb border fixup from global.
__global__ __launch_bounds__(256) void k_conv(const unsigned short* __restrict__ chgb,
                                              const float* __restrict__ wb,
                                              float* __restrict__ out){
  __shared__ float wefs[102];
  __shared__ float Gs[324];
  __shared__ float Cbs[18];
  const int tid = threadIdx.x;
  for(int i = tid; i < 444; i += 256){
    float v = wb[i];
    if(i < 102) wefs[i] = v;
    else if(i < 426) Gs[i - 102] = v;
    else Cbs[i - 426] = v;
  }
  __syncthreads();
  const int b   = blockIdx.y;
  const int oy  = blockIdx.x*4 + (tid >> 6);
  const int g   = tid & 63;
  const int ox0 = 4*g;
  const unsigned short* p0 = chgb + (size_t)(b*2 + 0)*260*264;
  const unsigned short* p1 = chgb + (size_t)(b*2 + 1)*260*264;
  uint4 raw0[5], raw1[5];
#pragma unroll
  for(int r = 0; r < 5; ++r){
    raw0[r] = *(const uint4*)(p0 + (oy + r)*264 + ox0 + 2);   // rows oy-2..oy+2 (ridx=gy+2)
    raw1[r] = *(const uint4*)(p1 + (oy + r)*264 + ox0 + 2);
  }
  float a0[4], a1[4];
#pragma unroll
  for(int q = 0; q < 4; ++q){ a0[q] = wefs[100]; a1[q] = wefs[101]; }
#pragma unroll
  for(int r = 0; r < 5; ++r){
    float f0[8], f1[8];
    const unsigned* u0 = (const unsigned*)&raw0[r];
    const unsigned* u1 = (const unsigned*)&raw1[r];
#pragma unroll
    for(int k = 0; k < 4; ++k){
      f0[2*k]   = __uint_as_float(u0[k] << 16);
      f0[2*k+1] = __uint_as_float(u0[k] & 0xffff0000u);
      f1[2*k]   = __uint_as_float(u1[k] << 16);
      f1[2*k+1] = __uint_as_float(u1[k] & 0xffff0000u);
    }
    const float* wa = &wefs[r*5];
    const float* wbv= &wefs[25 + r*5];
    const float* wc = &wefs[50 + r*5];
    const float* wd = &wefs[75 + r*5];
#pragma unroll
    for(int q = 0; q < 4; ++q){
#pragma unroll
      for(int u = 0; u < 5; ++u){
        a0[q] = fmaf(f0[q+u], wa[u], fmaf(f1[q+u], wbv[u], a0[q]));
        a1[q] = fmaf(f0[q+u], wc[u], fmaf(f1[q+u], wd[u], a1[q]));
      }
    }
  }
  if(oy == 0 || oy == 255 || g == 0 || g == 63){
#pragma unroll
    for(int q = 0; q < 4; ++q){
      const int ox = ox0 + q;
      if(oy != 0 && oy != 255 && ox != 0 && ox != 255) continue;
      for(int dy = 0; dy < 3; ++dy)
        for(int dx = 0; dx < 3; ++dx){
          const int gy2 = oy + dy - 1, gx2 = ox + dx - 1;
          if((unsigned)gy2 < 256u && (unsigned)gx2 < 256u) continue;
          const int dd = dy*3 + dx;
          float c0 = Cbs[dd], c1 = Cbs[9 + dd];
          for(int ky = 0; ky < 3; ++ky){
            const int sy = gy2 + ky - 1;
            if((unsigned)sy >= 256u) continue;
            for(int kx = 0; kx < 3; ++kx){
              const int sx = gx2 + kx - 1;
              if((unsigned)sx >= 256u) continue;
              const int k9 = ky*3 + kx;
              const float vx = bf2f(p0[(sy + 2)*264 + 4 + sx]);
              const float vy = bf2f(p1[(sy + 2)*264 + 4 + sx]);
              c0 += Gs[dd*9 + k9]*vx + Gs[81  + dd*9 + k9]*vy;
              c1 += Gs[162 + dd*9 + k9]*vx + Gs[243 + dd*9 + k9]*vy;
            }
          }
          a0[q] -= c0; a1[q] -= c1;
        }
    }
  }
  *(float4*)(out + ((size_t)(b*2+0)*256 + oy)*256 + ox0) = make_float4(a0[0], a0[1], a0[2], a0[3]);
  *(float4*)(out + ((size_t)(b*2+1)*256 + oy)*256 + ox0) = make_float4(a1[0], a1[1], a1[2], a1[3]);
}

extern "C" void kernel_launch(void* const* d_in, const int* in_sizes, int n_in,
                              void* d_out, int out_size, void* d_ws, size_t ws_size,
                              hipStream_t stream) {
  const float* tgt = (const float*)d_in[0];
  const float* ref = (const float*)d_in[1];
  const float* w1  = (const float*)d_in[2];
  const float* b1  = (const float*)d_in[3];
  const float* w2  = (const float*)d_in[4];
  const float* b2  = (const float*)d_in[5];
  float* out = (float*)d_out;

  // ws: dkwT @0 (5.83MB), dkwC @6MB (5.83MB), chgb @12MB (8.79MB bf16), wbuf @21MB
  float2* dkwT = (float2*)d_ws;
  float2* dkwC = (float2*)((char*)d_ws + (size_t)6*1024*1024);
  unsigned short* chgb = (unsigned short*)((char*)d_ws + (size_t)12*1024*1024);
  float* wbuf = (float*)((char*)d_ws + (size_t)21*1024*1024);

  k_rowfft<<<513, 1024, 0, stream>>>(tgt, ref, dkwT, w1, b1, w2, b2, wbuf);
  dim3 gc(12, 32);
  k_colfft<<<gc, 512, 0, stream>>>(dkwT, dkwC);
  k_ifft<<<2080, 256, 0, stream>>>(dkwC, ref, chgb);
  dim3 gv(64, 32);
  k_conv<<<gv, 256, 0, stream>>>(chgb, wbuf, out);
}